// Round 3
// baseline (1087.163 us; speedup 1.0000x reference)
//
#include <hip/hip_runtime.h>
#include <math.h>

#define EE 1024
#define ROWS_TOT 784   // 576 + 144 + 64
#define WWN 10752      // 768 + 3072 + 6912

typedef __attribute__((ext_vector_type(4))) float f4;
typedef __attribute__((ext_vector_type(4))) float f32x4;
typedef __attribute__((ext_vector_type(8))) __bf16 bf16x8;
typedef __attribute__((ext_vector_type(8))) unsigned short ushort8;

__device__ __forceinline__ unsigned short f2b(float x) {
    unsigned int u = __float_as_uint(x);
    unsigned int r = (u + 0x7fffu + ((u >> 16) & 1u)) >> 16;
    return (unsigned short)r;
}
__device__ __forceinline__ float b2f(unsigned short u) {
    unsigned int v = ((unsigned int)u) << 16;
    return __uint_as_float(v);
}

#define GLOAD16(g, l) __builtin_amdgcn_global_load_lds( \
    (const __attribute__((address_space(1))) unsigned int*)(g), \
    (__attribute__((address_space(3))) unsigned int*)(l), 16, 0, 0)

// ---------------------------------------------------------------------------
// Generic 2-phase double-buffered bf16 MFMA GEMM: C[M,N] = A[M,K] @ B[N,K]^T
// 128x128 tile, BK=32, 4 waves. STAGE(next) issued before compute(cur);
// one __syncthreads per K-step (its vmcnt(0) drain lands after ~176cy of work).
// ---------------------------------------------------------------------------
template<bool OB>
__global__ __launch_bounds__(256) void gemm2(
    const unsigned short* __restrict__ A, const unsigned short* __restrict__ Bw,
    const float* __restrict__ bias, void* __restrict__ Cv,
    int M, int N, int K)
{
    __shared__ unsigned short As[2][128 * 32];
    __shared__ unsigned short Bs[2][128 * 32];
    const int t = threadIdx.x;
    const int lane = t & 63;
    const int w = t >> 6;
    const int wm = w >> 1, wn = w & 1;

    int nwg = gridDim.x * gridDim.y;
    int bid = blockIdx.y * gridDim.x + blockIdx.x;
    int chunk = nwg >> 3;                    // nwg % 8 == 0 for all call sites
    int swz = (bid & 7) * chunk + (bid >> 3);
    int by = swz / gridDim.x, bx = swz % gridDim.x;
    const int m0 = by * 128, n0 = bx * 128;

    f32x4 acc[4][4] = {};

    const int sr = lane >> 2;
    const int sc = lane & 3;
    const unsigned short* gA0 = A + (size_t)(m0 + w * 32 + sr) * K + sc * 8;
    const unsigned short* gA1 = gA0 + (size_t)16 * K;
    const unsigned short* gB0 = Bw + (size_t)(n0 + w * 32 + sr) * K + sc * 8;
    const unsigned short* gB1 = gB0 + (size_t)16 * K;

    const int fr = lane & 15;
    const int kg = lane >> 4;

    const int nt = K >> 5;
    int cur = 0;

    auto STAGE = [&](int buf, int k0) {
        GLOAD16(gA0 + k0, &As[buf][w * 1024]);
        GLOAD16(gA1 + k0, &As[buf][w * 1024 + 512]);
        GLOAD16(gB0 + k0, &Bs[buf][w * 1024]);
        GLOAD16(gB1 + k0, &Bs[buf][w * 1024 + 512]);
    };

    STAGE(0, 0);
    __syncthreads();

    for (int tt = 0; tt < nt; ++tt) {
        if (tt + 1 < nt) STAGE(cur ^ 1, (tt + 1) * 32);
        const unsigned short* rdA = &As[cur][(wm * 64 + fr) * 32 + kg * 8];
        const unsigned short* rdB = &Bs[cur][(wn * 64 + fr) * 32 + kg * 8];
        bf16x8 af[4], bfr[4];
#pragma unroll
        for (int i = 0; i < 4; ++i) af[i]  = *(const bf16x8*)(rdA + i * 512);
#pragma unroll
        for (int j = 0; j < 4; ++j) bfr[j] = *(const bf16x8*)(rdB + j * 512);
#pragma unroll
        for (int i = 0; i < 4; ++i)
#pragma unroll
            for (int j = 0; j < 4; ++j)
                acc[i][j] = __builtin_amdgcn_mfma_f32_16x16x32_bf16(af[i], bfr[j], acc[i][j], 0, 0, 0);
        if (tt + 1 < nt) { __syncthreads(); cur ^= 1; }
    }

#pragma unroll
    for (int i = 0; i < 4; ++i) {
#pragma unroll
        for (int r = 0; r < 4; ++r) {
            int m = m0 + wm * 64 + i * 16 + kg * 4 + r;
#pragma unroll
            for (int j = 0; j < 4; ++j) {
                int n = n0 + wn * 64 + j * 16 + fr;
                float v = acc[i][j][r];
                if (bias) v += bias[n];
                if (OB) ((unsigned short*)Cv)[(size_t)m * N + n] = f2b(v);
                else    ((float*)Cv)[(size_t)m * N + n] = v;
            }
        }
    }
}

// ---------------------------------------------------------------------------
// Grouped value GEMM: all three levels in one dispatch. A rows are gathered
// from FEAT (bf16 [B*576, 768]) with per-K-chunk row indirection (replaces
// the materialized 2x2/3x3 rearranged arrays). B = fused weight WW
// [1024 rows(e), 10752 cols] with per-group column offset.
// grid = dim3(8, 392): y<288 -> level1, <360 -> level2, else level3.
// ---------------------------------------------------------------------------
__global__ __launch_bounds__(256) void gemm_val(
    const unsigned short* __restrict__ FEAT, const unsigned short* __restrict__ WW,
    const float* __restrict__ b1, const float* __restrict__ b2, const float* __restrict__ b3,
    unsigned short* __restrict__ VAL)
{
    __shared__ unsigned short As[2][128 * 32];
    __shared__ unsigned short Bs[2][128 * 32];
    const int t = threadIdx.x;
    const int lane = t & 63;
    const int w = t >> 6;
    const int wm = w >> 1, wn = w & 1;

    // bijective XCD swizzle; gridDim.x == 8
    int nwg = gridDim.x * gridDim.y;         // 3136
    int bid = blockIdx.y * gridDim.x + blockIdx.x;
    int chunk = nwg >> 3;
    int swz = (bid & 7) * chunk + (bid >> 3);
    int by = swz >> 3, bx = swz & 7;

    int g, my0, K, colOff, crowOff;
    const float* bias;
    if (by < 288)      { g = 0; my0 = by;       K = 768;  colOff = 0;    crowOff = 0;   bias = b1; }
    else if (by < 360) { g = 1; my0 = by - 288; K = 3072; colOff = 768;  crowOff = 576; bias = b2; }
    else               { g = 2; my0 = by - 360; K = 6912; colOff = 3840; crowOff = 720; bias = b3; }
    const int m0 = my0 * 128, n0 = bx * 128;

    f32x4 acc[4][4] = {};

    const int sr = lane >> 2;
    const int sc = lane & 3;
    // per-thread staged A rows (local m within group), source row bases
    int mrow0 = m0 + w * 32 + sr;
    int mrow1 = mrow0 + 16;
    int rb0, rb1;
    if (g == 0) {
        rb0 = mrow0; rb1 = mrow1;
    } else if (g == 1) {
        int b_ = mrow0 / 144, rl = mrow0 - b_ * 144;
        rb0 = b_ * 576 + (2 * (rl / 12)) * 24 + 2 * (rl % 12);
        b_ = mrow1 / 144; rl = mrow1 - b_ * 144;
        rb1 = b_ * 576 + (2 * (rl / 12)) * 24 + 2 * (rl % 12);
    } else {
        int b_ = mrow0 / 64, rl = mrow0 - b_ * 64;
        rb0 = b_ * 576 + (3 * (rl / 8)) * 24 + 3 * (rl % 8);
        b_ = mrow1 / 64; rl = mrow1 - b_ * 64;
        rb1 = b_ * 576 + (3 * (rl / 8)) * 24 + 3 * (rl % 8);
    }
    const unsigned short* gB0 = WW + (size_t)(n0 + w * 32 + sr) * WWN + colOff + sc * 8;
    const unsigned short* gB1 = gB0 + (size_t)16 * WWN;

    const int fr = lane & 15;
    const int kg = lane >> 4;

    const int nt = K >> 5;
    int cur = 0;

    auto STAGE = [&](int buf, int kt) {       // kt = K-tile index, k0 = kt*32
        int s = kt / 24;                      // chunk of 768 (=24 tiles)
        int within = (kt - s * 24) * 32;
        int add = 0;
        if (g == 1)      add = (s >> 1) * 24 + (s & 1);
        else if (g == 2) { int di = s / 3; add = di * 24 + (s - 3 * di); }
        GLOAD16(FEAT + (size_t)(rb0 + add) * 768 + within + sc * 8, &As[buf][w * 1024]);
        GLOAD16(FEAT + (size_t)(rb1 + add) * 768 + within + sc * 8, &As[buf][w * 1024 + 512]);
        GLOAD16(gB0 + (size_t)kt * 32, &Bs[buf][w * 1024]);
        GLOAD16(gB1 + (size_t)kt * 32, &Bs[buf][w * 1024 + 512]);
    };

    STAGE(0, 0);
    __syncthreads();

    for (int tt = 0; tt < nt; ++tt) {
        if (tt + 1 < nt) STAGE(cur ^ 1, tt + 1);
        const unsigned short* rdA = &As[cur][(wm * 64 + fr) * 32 + kg * 8];
        const unsigned short* rdB = &Bs[cur][(wn * 64 + fr) * 32 + kg * 8];
        bf16x8 af[4], bfr[4];
#pragma unroll
        for (int i = 0; i < 4; ++i) af[i]  = *(const bf16x8*)(rdA + i * 512);
#pragma unroll
        for (int j = 0; j < 4; ++j) bfr[j] = *(const bf16x8*)(rdB + j * 512);
#pragma unroll
        for (int i = 0; i < 4; ++i)
#pragma unroll
            for (int j = 0; j < 4; ++j)
                acc[i][j] = __builtin_amdgcn_mfma_f32_16x16x32_bf16(af[i], bfr[j], acc[i][j], 0, 0, 0);
        if (tt + 1 < nt) { __syncthreads(); cur ^= 1; }
    }

#pragma unroll
    for (int i = 0; i < 4; ++i) {
#pragma unroll
        for (int r = 0; r < 4; ++r) {
            int m = m0 + wm * 64 + i * 16 + kg * 4 + r;   // local m within group
            int crow;
            if (g == 0)      { int q = m / 576; crow = q * ROWS_TOT + (m - q * 576); }
            else if (g == 1) { int q = m / 144; crow = q * ROWS_TOT + 576 + (m - q * 144); }
            else             { int q = m / 64;  crow = q * ROWS_TOT + 720 + (m - q * 64); }
#pragma unroll
            for (int j = 0; j < 4; ++j) {
                int n = n0 + wn * 64 + j * 16 + fr;
                VAL[(size_t)crow * EE + n] = f2b(acc[i][j][r] + bias[n]);
            }
        }
    }
}

// fp32 -> bf16 straight copy (count divisible by 2048)
__global__ void f2b_kernel(const float* __restrict__ in, unsigned short* __restrict__ out) {
    size_t i = ((size_t)blockIdx.x * 256 + threadIdx.x) * 8;
    f4 a = *(const f4*)(in + i);
    f4 b = *(const f4*)(in + i + 4);
    ushort8 o;
    o[0] = f2b(a[0]); o[1] = f2b(a[1]); o[2] = f2b(a[2]); o[3] = f2b(a[3]);
    o[4] = f2b(b[0]); o[5] = f2b(b[1]); o[6] = f2b(b[2]); o[7] = f2b(b[3]);
    *(ushort8*)(out + i) = o;
}

// transpose-convert: in fp32 [R,C] -> out bf16 [C,R]
__global__ void tconv_kernel(const float* __restrict__ in, unsigned short* __restrict__ out,
                             int R, int C) {
    __shared__ float tile[32][33];
    int c0 = blockIdx.x * 32, r0 = blockIdx.y * 32;
    int tx = threadIdx.x & 31, ty = threadIdx.x >> 5;
#pragma unroll
    for (int i = 0; i < 32; i += 8)
        tile[ty + i][tx] = in[(size_t)(r0 + ty + i) * C + c0 + tx];
    __syncthreads();
#pragma unroll
    for (int i = 0; i < 32; i += 8)
        out[(size_t)(c0 + ty + i) * R + r0 + tx] = f2b(tile[tx][ty + i]);
}

// b'[e] = sum_j vp_w[e,j]*pb[j] + vp_b[e]
__global__ void fused_bias_kernel(const float* __restrict__ vp_w, const float* __restrict__ vp_b,
                                  const float* __restrict__ pb, float* __restrict__ bout)
{
    int e = blockIdx.x * 4 + (threadIdx.x >> 6);
    int lane = threadIdx.x & 63;
    float s = 0.f;
    for (int k = lane; k < EE; k += 64) s += vp_w[(size_t)e * EE + k] * pb[k];
#pragma unroll
    for (int o = 32; o > 0; o >>= 1) s += __shfl_down(s, o, 64);
    if (lane == 0) bout[e] = s + vp_b[e];
}

// ---------------------------------------------------------------------------
// Query branch (batch-independent), fp64 to match np reference indexing
// ---------------------------------------------------------------------------
__global__ void rg1_kernel(const float* __restrict__ qe, const float* __restrict__ w,
                           const float* __restrict__ b, double* __restrict__ h0)
{
    int o = blockIdx.x * 4 + (threadIdx.x >> 6);
    int lane = threadIdx.x & 63;
    int q = o >> 10, n = o & 1023;
    double s = 0.0;
    for (int k = lane; k < EE; k += 64)
        s += (double)qe[q * EE + k] * (double)w[(size_t)n * EE + k];
#pragma unroll
    for (int off = 32; off > 0; off >>= 1) s += __shfl_down(s, off, 64);
    if (lane == 0) h0[o] = s + (double)b[n];
}

__global__ void ln_gelu_kernel(const double* __restrict__ h0, const float* __restrict__ g,
                               const float* __restrict__ bb, double* __restrict__ h)
{
    __shared__ double red[256];
    __shared__ double stats[2];
    int q = blockIdx.x, t = threadIdx.x;
    double x[4];
#pragma unroll
    for (int i = 0; i < 4; ++i) x[i] = h0[q * 1024 + t + i * 256];
    double s = x[0] + x[1] + x[2] + x[3];
    red[t] = s; __syncthreads();
    for (int o = 128; o; o >>= 1) { if (t < o) red[t] += red[t + o]; __syncthreads(); }
    if (t == 0) stats[0] = red[0] / 1024.0;
    __syncthreads();
    double mean = stats[0];
    double d = 0.0;
#pragma unroll
    for (int i = 0; i < 4; ++i) { double dd = x[i] - mean; d += dd * dd; }
    red[t] = d; __syncthreads();
    for (int o = 128; o; o >>= 1) { if (t < o) red[t] += red[t + o]; __syncthreads(); }
    if (t == 0) stats[1] = red[0] / 1024.0;
    __syncthreads();
    double inv = 1.0 / sqrt(stats[1] + 1e-5);
#pragma unroll
    for (int i = 0; i < 4; ++i) {
        int c = t + i * 256;
        double y = (x[i] - mean) * inv * (double)g[c] + (double)bb[c];
        h[q * 1024 + c] = y * 0.5 * (1.0 + erf(y * 0.70710678118654752440));
    }
}

__global__ void rp_kernel(const double* __restrict__ h, const float* __restrict__ w2,
                          const float* __restrict__ b2, double* __restrict__ rp)
{
    int o = blockIdx.x * 4 + (threadIdx.x >> 6);
    int lane = threadIdx.x & 63;
    int q = o >> 1, r = o & 1;
    double s = 0.0;
    for (int k = lane; k < EE; k += 64)
        s += h[q * 1024 + k] * (double)w2[r * 1024 + k];
#pragma unroll
    for (int off = 32; off > 0; off >>= 1) s += __shfl_down(s, off, 64);
    if (lane == 0) rp[o] = 1.0 / (1.0 + exp(-(s + (double)b2[r])));
}

__global__ void offidx_kernel(const float* __restrict__ qe, const float* __restrict__ so_w,
                              const float* __restrict__ so_b, const float* __restrict__ aw_w,
                              const float* __restrict__ aw_b, const double* __restrict__ rp,
                              float* __restrict__ awf, int* __restrict__ idxv)
{
    __shared__ double offv[128];
    __shared__ double logit[64];
    int q = blockIdx.x, t = threadIdx.x;
    if (t < 128) {
        double s = 0.0;
        for (int k = 0; k < EE; ++k) s += (double)qe[q * EE + k] * (double)so_w[(size_t)t * EE + k];
        offv[t] = s + (double)so_b[t];
    } else if (t < 192) {
        int n = t - 128;
        double s = 0.0;
        for (int k = 0; k < EE; ++k) s += (double)qe[q * EE + k] * (double)aw_w[(size_t)n * EE + k];
        logit[n] = s + (double)aw_b[n];
    }
    __syncthreads();
    if (t < 64) {
        int hh = t >> 2, p = t & 3;
        double l0 = logit[hh * 4 + 0], l1 = logit[hh * 4 + 1];
        double l2 = logit[hh * 4 + 2], l3 = logit[hh * 4 + 3];
        double m = fmax(fmax(l0, l1), fmax(l2, l3));
        double den = exp(l0 - m) + exp(l1 - m) + exp(l2 - m) + exp(l3 - m);
        awf[(q * 16 + hh) * 4 + p] = (float)(exp(logit[hh * 4 + p] - m) / den);
        const int Wss[3] = {24, 12, 8};
        const int starts[3] = {0, 576, 720};
        double ox = offv[(hh * 4 + p) * 2 + 0], oy = offv[(hh * 4 + p) * 2 + 1];
        double rx = rp[q * 2 + 0], ry = rp[q * 2 + 1];
#pragma unroll
        for (int l = 0; l < 3; ++l) {
            int Ws = Wss[l];
            double sx = rx + ox; sx = sx < 0.0 ? 0.0 : (sx > 1.0 ? 1.0 : sx);
            double sy = ry + oy; sy = sy < 0.0 ? 0.0 : (sy > 1.0 ? 1.0 : sy);
            int x0 = (int)floor(sx * (double)(Ws - 1));
            int y0 = (int)floor(sy * (double)(Ws - 1));
            idxv[((l * 64 + q) * 16 + hh) * 4 + p] = starts[l] + y0 * Ws + x0;
        }
    }
}

// out0[b,q,h,:] = sum_{l,p} aw[q,h,p] * value[b, idx[l,q,h,p], h, :]   (bf16)
__global__ void gather_kernel(const unsigned short* __restrict__ value, const float* __restrict__ awf,
                              const int* __restrict__ idxv, unsigned short* __restrict__ out0)
{
    int unit = blockIdx.x * 4 + (threadIdx.x >> 6);
    int lane = threadIdx.x & 63;
    int b = unit >> 10;
    int rem = unit & 1023;
    int q = rem >> 4, h = rem & 15;
    float acc = 0.f;
#pragma unroll
    for (int l = 0; l < 3; ++l)
#pragma unroll
        for (int p = 0; p < 4; ++p) {
            int row = idxv[((l * 64 + q) * 16 + h) * 4 + p];
            float wgt = awf[(q * 16 + h) * 4 + p];
            acc += wgt * b2f(value[((size_t)(b * ROWS_TOT + row)) * 1024 + h * 64 + lane]);
        }
    out0[((size_t)(b * 64 + q)) * 1024 + h * 64 + lane] = f2b(acc);
}

// fp32 LayerNorm over 1024, output bf16
__global__ void ln_bf16_kernel(const float* __restrict__ x, const float* __restrict__ g,
                               const float* __restrict__ bb, unsigned short* __restrict__ y)
{
    __shared__ float red[256];
    __shared__ float stats[2];
    int r = blockIdx.x, t = threadIdx.x;
    float v[4];
#pragma unroll
    for (int i = 0; i < 4; ++i) v[i] = x[(size_t)r * 1024 + t + i * 256];
    float s = v[0] + v[1] + v[2] + v[3];
    red[t] = s; __syncthreads();
    for (int o = 128; o; o >>= 1) { if (t < o) red[t] += red[t + o]; __syncthreads(); }
    if (t == 0) stats[0] = red[0] / 1024.f;
    __syncthreads();
    float mean = stats[0];
    float d = 0.f;
#pragma unroll
    for (int i = 0; i < 4; ++i) { float dd = v[i] - mean; d += dd * dd; }
    red[t] = d; __syncthreads();
    for (int o = 128; o; o >>= 1) { if (t < o) red[t] += red[t + o]; __syncthreads(); }
    if (t == 0) stats[1] = red[0] / 1024.f;
    __syncthreads();
    float inv = 1.f / sqrtf(stats[1] + 1e-5f);
#pragma unroll
    for (int i = 0; i < 4; ++i) {
        int c = t + i * 256;
        y[(size_t)r * 1024 + c] = f2b((v[i] - mean) * inv * g[c] + bb[c]);
    }
}

extern "C" void kernel_launch(void* const* d_in, const int* in_sizes, int n_in,
                              void* d_out, int out_size, void* d_ws, size_t ws_size,
                              hipStream_t stream)
{
    const float* features  = (const float*)d_in[0];
    const float* p1_w      = (const float*)d_in[1];
    const float* p2_w      = (const float*)d_in[3];
    const float* p3_w      = (const float*)d_in[5];
    const float* p1_b      = (const float*)d_in[2];
    const float* p2_b      = (const float*)d_in[4];
    const float* p3_b      = (const float*)d_in[6];
    const float* query_emb = (const float*)d_in[7];
    const float* rg_w1     = (const float*)d_in[8];
    const float* rg_b1     = (const float*)d_in[9];
    const float* rg_g      = (const float*)d_in[10];
    const float* rg_b      = (const float*)d_in[11];
    const float* rg_w2     = (const float*)d_in[12];
    const float* rg_b2     = (const float*)d_in[13];
    const float* so_w      = (const float*)d_in[14];
    const float* so_b      = (const float*)d_in[15];
    const float* aw_w      = (const float*)d_in[16];
    const float* aw_b      = (const float*)d_in[17];
    const float* vp_w      = (const float*)d_in[18];
    const float* vp_b      = (const float*)d_in[19];
    const float* op_w      = (const float*)d_in[20];
    const float* op_b      = (const float*)d_in[21];
    const float* fln_g     = (const float*)d_in[22];
    const float* fln_b     = (const float*)d_in[23];
    const float* fin_w     = (const float*)d_in[24];
    const float* fin_b     = (const float*)d_in[25];
    float* out = (float*)d_out;

    // ---- workspace layout (bytes) ----
    char* p = (char*)d_ws;
    unsigned short* FEAT = (unsigned short*)p; p += 56623104;   // bf16 features [B*576,768]
    unsigned short* PT   = (unsigned short*)p; p += 22020096;   // [10752,1024] stacked p_w^T
    unsigned short* WW   = (unsigned short*)p; p += 22020096;   // [1024,10752] fused weights
    unsigned short* VPW  = (unsigned short*)p; p += 2097152;
    unsigned short* VAL  = (unsigned short*)p; p += 102760448;  // value bf16 [64*784,1024]
    unsigned short* OUT0 = (unsigned short*)p; p += 8388608;
    float*          OUT1 = (float*)p;          p += 16777216;
    unsigned short* LNO  = (unsigned short*)p; p += 8388608;
    unsigned short* OPW  = (unsigned short*)p; p += 2097152;
    unsigned short* FINW = (unsigned short*)p; p += 2097152;
    float* b1p  = (float*)p; p += 4096;
    float* b2p  = (float*)p; p += 4096;
    float* b3p  = (float*)p; p += 4096;
    float* awf  = (float*)p; p += 16384;
    int*   idxv = (int*)p;   p += 49152;
    double* h0  = (double*)p; p += 524288;
    double* hb  = (double*)p; p += 524288;
    double* rp  = (double*)p; p += 1024;

    dim3 blk(256);

    // ---- query branch (fp64, batch-independent) ----
    rg1_kernel<<<16384, blk, 0, stream>>>(query_emb, rg_w1, rg_b1, h0);
    ln_gelu_kernel<<<64, blk, 0, stream>>>(h0, rg_g, rg_b, hb);
    rp_kernel<<<32, blk, 0, stream>>>(hb, rg_w2, rg_b2, rp);
    offidx_kernel<<<64, blk, 0, stream>>>(query_emb, so_w, so_b, aw_w, aw_b, rp, awf, idxv);

    // ---- conversions ----
    f2b_kernel<<<512, blk, 0, stream>>>(vp_w, VPW);
    f2b_kernel<<<512, blk, 0, stream>>>(op_w, OPW);
    f2b_kernel<<<512, blk, 0, stream>>>(fin_w, FINW);
    f2b_kernel<<<13824, blk, 0, stream>>>(features, FEAT);
    fused_bias_kernel<<<256, blk, 0, stream>>>(vp_w, vp_b, p1_b, b1p);
    fused_bias_kernel<<<256, blk, 0, stream>>>(vp_w, vp_b, p2_b, b2p);
    fused_bias_kernel<<<256, blk, 0, stream>>>(vp_w, vp_b, p3_b, b3p);

    // ---- stacked transposes: PT rows [0,768)=p1^T, [768,3840)=p2^T, [3840,10752)=p3^T
    tconv_kernel<<<dim3(24, 32),  blk, 0, stream>>>(p1_w, PT,               1024, 768);
    tconv_kernel<<<dim3(96, 32),  blk, 0, stream>>>(p2_w, PT + 768  * 1024, 1024, 3072);
    tconv_kernel<<<dim3(216, 32), blk, 0, stream>>>(p3_w, PT + 3840 * 1024, 1024, 6912);

    // ---- all fused weights in one GEMM: WW[1024,10752] = VPW @ PT^T ----
    gemm2<true><<<dim3(84, 8), blk, 0, stream>>>(VPW, PT, nullptr, WW, 1024, WWN, 1024);

    // ---- grouped value GEMM (all 3 levels, one dispatch) ----
    gemm_val<<<dim3(8, 392), blk, 0, stream>>>(FEAT, WW, b1p, b2p, b3p, VAL);

    // ---- deformable gather ----
    gather_kernel<<<16384, blk, 0, stream>>>(VAL, awf, idxv, OUT0);

    // ---- output projection, LN, final projection ----
    gemm2<false><<<dim3(8, 32), blk, 0, stream>>>(OUT0, OPW, op_b, OUT1, 4096, 1024, 1024);
    ln_bf16_kernel<<<4096, blk, 0, stream>>>(OUT1, fln_g, fln_b, LNO);
    gemm2<false><<<dim3(8, 32), blk, 0, stream>>>(LNO, FINW, fin_b, out, 4096, 1024, 1024);
}

// Round 4
// 581.309 us; speedup vs baseline: 1.8702x; 1.8702x over previous
//
#include <hip/hip_runtime.h>
#include <math.h>

#define EE 1024
#define ROWS_TOT 784   // 576 + 144 + 64
#define WWN 10752      // 768 + 3072 + 6912

typedef __attribute__((ext_vector_type(4))) float f4;
typedef __attribute__((ext_vector_type(4))) float f32x4;
typedef __attribute__((ext_vector_type(8))) __bf16 bf16x8;
typedef __attribute__((ext_vector_type(8))) unsigned short ushort8;

__device__ __forceinline__ unsigned short f2b(float x) {
    unsigned int u = __float_as_uint(x);
    unsigned int r = (u + 0x7fffu + ((u >> 16) & 1u)) >> 16;
    return (unsigned short)r;
}
__device__ __forceinline__ float b2f(unsigned short u) {
    unsigned int v = ((unsigned int)u) << 16;
    return __uint_as_float(v);
}

#define GLOAD16(g, l) __builtin_amdgcn_global_load_lds( \
    (const __attribute__((address_space(1))) unsigned int*)(g), \
    (__attribute__((address_space(3))) unsigned int*)(l), 16, 0, 0)

// ---------------------------------------------------------------------------
// 2-phase double-buffered bf16 MFMA GEMM: C[M,N] = A[M,K] @ B[N,K]^T + bias
// 128x128 tile, BK=32, 4 waves. STAGE(next) issued before compute(cur);
// one __syncthreads per K-step.
// ---------------------------------------------------------------------------
template<bool OB>
__global__ __launch_bounds__(256) void gemm2(
    const unsigned short* __restrict__ A, const unsigned short* __restrict__ Bw,
    const float* __restrict__ bias, void* __restrict__ Cv,
    int M, int N, int K)
{
    __shared__ unsigned short As[2][128 * 32];
    __shared__ unsigned short Bs[2][128 * 32];
    const int t = threadIdx.x;
    const int lane = t & 63;
    const int w = t >> 6;
    const int wm = w >> 1, wn = w & 1;

    int nwg = gridDim.x * gridDim.y;
    int bid = blockIdx.y * gridDim.x + blockIdx.x;
    int chunk = nwg >> 3;                    // nwg % 8 == 0 for all call sites
    int swz = (bid & 7) * chunk + (bid >> 3);
    int by = swz / gridDim.x, bx = swz % gridDim.x;
    const int m0 = by * 128, n0 = bx * 128;

    f32x4 acc[4][4] = {};

    const int sr = lane >> 2;
    const int sc = lane & 3;
    const unsigned short* gA0 = A + (size_t)(m0 + w * 32 + sr) * K + sc * 8;
    const unsigned short* gA1 = gA0 + (size_t)16 * K;
    const unsigned short* gB0 = Bw + (size_t)(n0 + w * 32 + sr) * K + sc * 8;
    const unsigned short* gB1 = gB0 + (size_t)16 * K;

    const int fr = lane & 15;
    const int kg = lane >> 4;

    const int nt = K >> 5;
    int cur = 0;

    auto STAGE = [&](int buf, int k0) {
        GLOAD16(gA0 + k0, &As[buf][w * 1024]);
        GLOAD16(gA1 + k0, &As[buf][w * 1024 + 512]);
        GLOAD16(gB0 + k0, &Bs[buf][w * 1024]);
        GLOAD16(gB1 + k0, &Bs[buf][w * 1024 + 512]);
    };

    STAGE(0, 0);
    __syncthreads();

    for (int tt = 0; tt < nt; ++tt) {
        if (tt + 1 < nt) STAGE(cur ^ 1, (tt + 1) * 32);
        const unsigned short* rdA = &As[cur][(wm * 64 + fr) * 32 + kg * 8];
        const unsigned short* rdB = &Bs[cur][(wn * 64 + fr) * 32 + kg * 8];
        bf16x8 af[4], bfr[4];
#pragma unroll
        for (int i = 0; i < 4; ++i) af[i]  = *(const bf16x8*)(rdA + i * 512);
#pragma unroll
        for (int j = 0; j < 4; ++j) bfr[j] = *(const bf16x8*)(rdB + j * 512);
#pragma unroll
        for (int i = 0; i < 4; ++i)
#pragma unroll
            for (int j = 0; j < 4; ++j)
                acc[i][j] = __builtin_amdgcn_mfma_f32_16x16x32_bf16(af[i], bfr[j], acc[i][j], 0, 0, 0);
        if (tt + 1 < nt) { __syncthreads(); cur ^= 1; }
    }

#pragma unroll
    for (int i = 0; i < 4; ++i) {
#pragma unroll
        for (int r = 0; r < 4; ++r) {
            int m = m0 + wm * 64 + i * 16 + kg * 4 + r;
#pragma unroll
            for (int j = 0; j < 4; ++j) {
                int n = n0 + wn * 64 + j * 16 + fr;
                float v = acc[i][j][r];
                if (bias) v += bias[n];
                if (OB) ((unsigned short*)Cv)[(size_t)m * N + n] = f2b(v);
                else    ((float*)Cv)[(size_t)m * N + n] = v;
            }
        }
    }
}

// ---------------------------------------------------------------------------
// Per-level value GEMM: A rows gathered from FEAT [B*576,768], B = WW slice.
// MODE 1/2/3 = level. SPLIT: write fp32 partial (no bias) for K-chunk
// blockIdx.z; else write bf16 VAL rows (bias added).
// ktCount = K-steps per z-chunk (BK=32).
// ---------------------------------------------------------------------------
template<int MODE, bool SPLIT>
__global__ __launch_bounds__(256) void gemm_vlv(
    const unsigned short* __restrict__ FEAT, const unsigned short* __restrict__ WW,
    const float* __restrict__ bias, void* __restrict__ outp, int ktCount)
{
    constexpr int gw = (MODE == 1) ? 24 : (MODE == 2 ? 12 : 8);
    constexpr int Rl = gw * gw;                                   // 576/144/64
    constexpr int colOff = (MODE == 1) ? 0 : (MODE == 2 ? 768 : 3840);
    constexpr int rowOff = (MODE == 1) ? 0 : (MODE == 2 ? 576 : 720);

    __shared__ unsigned short As[2][128 * 32];
    __shared__ unsigned short Bs[2][128 * 32];
    const int t = threadIdx.x;
    const int lane = t & 63;
    const int w = t >> 6;
    const int wm = w >> 1, wn = w & 1;

    int nwg = gridDim.x * gridDim.y;
    int bid = blockIdx.y * gridDim.x + blockIdx.x;
    int chunk = nwg >> 3;
    int swz = (bid & 7) * chunk + (bid >> 3);
    int by = swz / gridDim.x, bx = swz % gridDim.x;
    const int m0 = by * 128, n0 = bx * 128;
    const int ktBase = blockIdx.z * ktCount;

    f32x4 acc[4][4] = {};

    const int sr = lane >> 2;
    const int sc = lane & 3;
    int mrow0 = m0 + w * 32 + sr;
    int mrow1 = mrow0 + 16;
    int rb0, rb1;
    if (MODE == 1) { rb0 = mrow0; rb1 = mrow1; }
    else {
        int b_ = mrow0 / Rl, rl = mrow0 - b_ * Rl;
        rb0 = b_ * 576 + (MODE * (rl / gw)) * 24 + MODE * (rl % gw);
        b_ = mrow1 / Rl; rl = mrow1 - b_ * Rl;
        rb1 = b_ * 576 + (MODE * (rl / gw)) * 24 + MODE * (rl % gw);
    }
    const unsigned short* gB0 = WW + (size_t)(n0 + w * 32 + sr) * WWN + colOff + sc * 8;
    const unsigned short* gB1 = gB0 + (size_t)16 * WWN;

    const int fr = lane & 15;
    const int kg = lane >> 4;
    int cur = 0;

    auto STAGE = [&](int buf, int ktl) {
        int kt = ktBase + ktl;
        int s = kt / 24;                       // which 768-chunk
        int within = (kt - s * 24) * 32;
        int add = 0;
        if (MODE == 2)      add = (s >> 1) * 24 + (s & 1);
        else if (MODE == 3) { int di = s / 3; add = di * 24 + (s - 3 * di); }
        GLOAD16(FEAT + (size_t)(rb0 + add) * 768 + within + sc * 8, &As[buf][w * 1024]);
        GLOAD16(FEAT + (size_t)(rb1 + add) * 768 + within + sc * 8, &As[buf][w * 1024 + 512]);
        GLOAD16(gB0 + (size_t)kt * 32, &Bs[buf][w * 1024]);
        GLOAD16(gB1 + (size_t)kt * 32, &Bs[buf][w * 1024 + 512]);
    };

    STAGE(0, 0);
    __syncthreads();

    for (int tt = 0; tt < ktCount; ++tt) {
        if (tt + 1 < ktCount) STAGE(cur ^ 1, tt + 1);
        const unsigned short* rdA = &As[cur][(wm * 64 + fr) * 32 + kg * 8];
        const unsigned short* rdB = &Bs[cur][(wn * 64 + fr) * 32 + kg * 8];
        bf16x8 af[4], bfr[4];
#pragma unroll
        for (int i = 0; i < 4; ++i) af[i]  = *(const bf16x8*)(rdA + i * 512);
#pragma unroll
        for (int j = 0; j < 4; ++j) bfr[j] = *(const bf16x8*)(rdB + j * 512);
#pragma unroll
        for (int i = 0; i < 4; ++i)
#pragma unroll
            for (int j = 0; j < 4; ++j)
                acc[i][j] = __builtin_amdgcn_mfma_f32_16x16x32_bf16(af[i], bfr[j], acc[i][j], 0, 0, 0);
        if (tt + 1 < ktCount) { __syncthreads(); cur ^= 1; }
    }

#pragma unroll
    for (int i = 0; i < 4; ++i) {
#pragma unroll
        for (int r = 0; r < 4; ++r) {
            int m = m0 + wm * 64 + i * 16 + kg * 4 + r;     // local level row
#pragma unroll
            for (int j = 0; j < 4; ++j) {
                int n = n0 + wn * 64 + j * 16 + fr;
                if (SPLIT) {
                    float* P = (float*)outp + (size_t)blockIdx.z * (4096 * 1024);
                    P[(size_t)m * EE + n] = acc[i][j][r];
                } else {
                    int b_o = m / Rl, rl_o = m - (m / Rl) * Rl;
                    int crow = b_o * ROWS_TOT + rowOff + rl_o;
                    ((unsigned short*)outp)[(size_t)crow * EE + n] = f2b(acc[i][j][r] + bias[n]);
                }
            }
        }
    }
}

// reduce level-3 split-K partials: VAL rows 720..783 per batch
__global__ void reduce3_kernel(const float* __restrict__ P, const float* __restrict__ b3,
                               unsigned short* __restrict__ VAL)
{
    int idx = blockIdx.x * 256 + threadIdx.x;   // 524288 units of 8 elems
    size_t e0 = (size_t)idx * 8;
    int m = (int)(e0 >> 10);
    int n = (int)(e0 & 1023);
    f4 a0 = *(const f4*)(P + e0);
    f4 a1 = *(const f4*)(P + e0 + 4);
    f4 c0 = *(const f4*)(P + 4194304 + e0);
    f4 c1 = *(const f4*)(P + 4194304 + e0 + 4);
    f4 d0 = *(const f4*)(P + 8388608 + e0);
    f4 d1 = *(const f4*)(P + 8388608 + e0 + 4);
    int crow = (m >> 6) * ROWS_TOT + 720 + (m & 63);
    ushort8 o;
#pragma unroll
    for (int i = 0; i < 4; ++i) o[i]     = f2b(a0[i] + c0[i] + d0[i] + b3[n + i]);
#pragma unroll
    for (int i = 0; i < 4; ++i) o[4 + i] = f2b(a1[i] + c1[i] + d1[i] + b3[n + 4 + i]);
    *(ushort8*)(VAL + (size_t)crow * EE + n) = o;
}

// split-K (z in {0,1}) partial GEMM for the two 4096x1024x1024 epilogue GEMMs
__global__ __launch_bounds__(256) void gemm_pk(
    const unsigned short* __restrict__ A, const unsigned short* __restrict__ Bw,
    float* __restrict__ P)
{
    __shared__ unsigned short As[2][128 * 32];
    __shared__ unsigned short Bs[2][128 * 32];
    const int t = threadIdx.x;
    const int lane = t & 63;
    const int w = t >> 6;
    const int wm = w >> 1, wn = w & 1;
    const int K = 1024;

    int nwg = gridDim.x * gridDim.y;
    int bid = blockIdx.y * gridDim.x + blockIdx.x;
    int chunk = nwg >> 3;
    int swz = (bid & 7) * chunk + (bid >> 3);
    int by = swz / gridDim.x, bx = swz % gridDim.x;
    const int m0 = by * 128, n0 = bx * 128;
    const int kBase = blockIdx.z * 512;

    f32x4 acc[4][4] = {};
    const int sr = lane >> 2;
    const int sc = lane & 3;
    const unsigned short* gA0 = A + (size_t)(m0 + w * 32 + sr) * K + kBase + sc * 8;
    const unsigned short* gA1 = gA0 + (size_t)16 * K;
    const unsigned short* gB0 = Bw + (size_t)(n0 + w * 32 + sr) * K + kBase + sc * 8;
    const unsigned short* gB1 = gB0 + (size_t)16 * K;
    const int fr = lane & 15;
    const int kg = lane >> 4;
    int cur = 0;

    auto STAGE = [&](int buf, int k0) {
        GLOAD16(gA0 + k0, &As[buf][w * 1024]);
        GLOAD16(gA1 + k0, &As[buf][w * 1024 + 512]);
        GLOAD16(gB0 + k0, &Bs[buf][w * 1024]);
        GLOAD16(gB1 + k0, &Bs[buf][w * 1024 + 512]);
    };

    STAGE(0, 0);
    __syncthreads();
    for (int tt = 0; tt < 16; ++tt) {
        if (tt + 1 < 16) STAGE(cur ^ 1, (tt + 1) * 32);
        const unsigned short* rdA = &As[cur][(wm * 64 + fr) * 32 + kg * 8];
        const unsigned short* rdB = &Bs[cur][(wn * 64 + fr) * 32 + kg * 8];
        bf16x8 af[4], bfr[4];
#pragma unroll
        for (int i = 0; i < 4; ++i) af[i]  = *(const bf16x8*)(rdA + i * 512);
#pragma unroll
        for (int j = 0; j < 4; ++j) bfr[j] = *(const bf16x8*)(rdB + j * 512);
#pragma unroll
        for (int i = 0; i < 4; ++i)
#pragma unroll
            for (int j = 0; j < 4; ++j)
                acc[i][j] = __builtin_amdgcn_mfma_f32_16x16x32_bf16(af[i], bfr[j], acc[i][j], 0, 0, 0);
        if (tt + 1 < 16) { __syncthreads(); cur ^= 1; }
    }

    float* Pz = P + (size_t)blockIdx.z * (4096 * 1024);
#pragma unroll
    for (int i = 0; i < 4; ++i)
#pragma unroll
        for (int r = 0; r < 4; ++r) {
            int m = m0 + wm * 64 + i * 16 + kg * 4 + r;
#pragma unroll
            for (int j = 0; j < 4; ++j) {
                int n = n0 + wn * 64 + j * 16 + fr;
                Pz[(size_t)m * EE + n] = acc[i][j][r];
            }
        }
}

// fp32 -> bf16 straight copy (count divisible by 2048)
__global__ void f2b_kernel(const float* __restrict__ in, unsigned short* __restrict__ out) {
    size_t i = ((size_t)blockIdx.x * 256 + threadIdx.x) * 8;
    f4 a = *(const f4*)(in + i);
    f4 b = *(const f4*)(in + i + 4);
    ushort8 o;
    o[0] = f2b(a[0]); o[1] = f2b(a[1]); o[2] = f2b(a[2]); o[3] = f2b(a[3]);
    o[4] = f2b(b[0]); o[5] = f2b(b[1]); o[6] = f2b(b[2]); o[7] = f2b(b[3]);
    *(ushort8*)(out + i) = o;
}

// three 1024x1024 weight conversions in one dispatch (512 blocks each)
__global__ void f2b3_kernel(const float* __restrict__ a, unsigned short* __restrict__ oa,
                            const float* __restrict__ b, unsigned short* __restrict__ ob,
                            const float* __restrict__ c, unsigned short* __restrict__ oc) {
    int blk = blockIdx.x;
    const float* in; unsigned short* out;
    if (blk < 512)      { in = a; out = oa; }
    else if (blk < 1024){ in = b; out = ob; blk -= 512; }
    else                { in = c; out = oc; blk -= 1024; }
    size_t i = ((size_t)blk * 256 + threadIdx.x) * 8;
    f4 x = *(const f4*)(in + i);
    f4 y = *(const f4*)(in + i + 4);
    ushort8 o;
    o[0] = f2b(x[0]); o[1] = f2b(x[1]); o[2] = f2b(x[2]); o[3] = f2b(x[3]);
    o[4] = f2b(y[0]); o[5] = f2b(y[1]); o[6] = f2b(y[2]); o[7] = f2b(y[3]);
    *(ushort8*)(out + i) = o;
}

// transpose-convert: in fp32 [R,C] -> out bf16 [C,R]
__global__ void tconv_kernel(const float* __restrict__ in, unsigned short* __restrict__ out,
                             int R, int C) {
    __shared__ float tile[32][33];
    int c0 = blockIdx.x * 32, r0 = blockIdx.y * 32;
    int tx = threadIdx.x & 31, ty = threadIdx.x >> 5;
#pragma unroll
    for (int i = 0; i < 32; i += 8)
        tile[ty + i][tx] = in[(size_t)(r0 + ty + i) * C + c0 + tx];
    __syncthreads();
#pragma unroll
    for (int i = 0; i < 32; i += 8)
        out[(size_t)(c0 + ty + i) * R + r0 + tx] = f2b(tile[tx][ty + i]);
}

// three fused biases in one dispatch: b'[e] = vp_w[e,:]·pb + vp_b[e]
__global__ void fused_bias3_kernel(const float* __restrict__ vp_w, const float* __restrict__ vp_b,
                                   const float* __restrict__ pb1, const float* __restrict__ pb2,
                                   const float* __restrict__ pb3,
                                   float* __restrict__ o1, float* __restrict__ o2, float* __restrict__ o3)
{
    int blk = blockIdx.x;
    const float* pb; float* bout;
    if (blk < 256)      { pb = pb1; bout = o1; }
    else if (blk < 512) { pb = pb2; bout = o2; blk -= 256; }
    else                { pb = pb3; bout = o3; blk -= 512; }
    int e = blk * 4 + (threadIdx.x >> 6);
    int lane = threadIdx.x & 63;
    float s = 0.f;
    for (int k = lane; k < EE; k += 64) s += vp_w[(size_t)e * EE + k] * pb[k];
#pragma unroll
    for (int o = 32; o > 0; o >>= 1) s += __shfl_down(s, o, 64);
    if (lane == 0) bout[e] = s + vp_b[e];
}

// ---------------------------------------------------------------------------
// Query branch (batch-independent), fp64 — DO NOT ALTER (index-snap safety)
// ---------------------------------------------------------------------------
__global__ void rg1_kernel(const float* __restrict__ qe, const float* __restrict__ w,
                           const float* __restrict__ b, double* __restrict__ h0)
{
    int o = blockIdx.x * 4 + (threadIdx.x >> 6);
    int lane = threadIdx.x & 63;
    int q = o >> 10, n = o & 1023;
    double s = 0.0;
    for (int k = lane; k < EE; k += 64)
        s += (double)qe[q * EE + k] * (double)w[(size_t)n * EE + k];
#pragma unroll
    for (int off = 32; off > 0; off >>= 1) s += __shfl_down(s, off, 64);
    if (lane == 0) h0[o] = s + (double)b[n];
}

__global__ void ln_gelu_kernel(const double* __restrict__ h0, const float* __restrict__ g,
                               const float* __restrict__ bb, double* __restrict__ h)
{
    __shared__ double red[256];
    __shared__ double stats[2];
    int q = blockIdx.x, t = threadIdx.x;
    double x[4];
#pragma unroll
    for (int i = 0; i < 4; ++i) x[i] = h0[q * 1024 + t + i * 256];
    double s = x[0] + x[1] + x[2] + x[3];
    red[t] = s; __syncthreads();
    for (int o = 128; o; o >>= 1) { if (t < o) red[t] += red[t + o]; __syncthreads(); }
    if (t == 0) stats[0] = red[0] / 1024.0;
    __syncthreads();
    double mean = stats[0];
    double d = 0.0;
#pragma unroll
    for (int i = 0; i < 4; ++i) { double dd = x[i] - mean; d += dd * dd; }
    red[t] = d; __syncthreads();
    for (int o = 128; o; o >>= 1) { if (t < o) red[t] += red[t + o]; __syncthreads(); }
    if (t == 0) stats[1] = red[0] / 1024.0;
    __syncthreads();
    double inv = 1.0 / sqrt(stats[1] + 1e-5);
#pragma unroll
    for (int i = 0; i < 4; ++i) {
        int c = t + i * 256;
        double y = (x[i] - mean) * inv * (double)g[c] + (double)bb[c];
        h[q * 1024 + c] = y * 0.5 * (1.0 + erf(y * 0.70710678118654752440));
    }
}

__global__ void rp_kernel(const double* __restrict__ h, const float* __restrict__ w2,
                          const float* __restrict__ b2, double* __restrict__ rp)
{
    int o = blockIdx.x * 4 + (threadIdx.x >> 6);
    int lane = threadIdx.x & 63;
    int q = o >> 1, r = o & 1;
    double s = 0.0;
    for (int k = lane; k < EE; k += 64)
        s += h[q * 1024 + k] * (double)w2[r * 1024 + k];
#pragma unroll
    for (int off = 32; off > 0; off >>= 1) s += __shfl_down(s, off, 64);
    if (lane == 0) rp[o] = 1.0 / (1.0 + exp(-(s + (double)b2[r])));
}

__global__ void offidx_kernel(const float* __restrict__ qe, const float* __restrict__ so_w,
                              const float* __restrict__ so_b, const float* __restrict__ aw_w,
                              const float* __restrict__ aw_b, const double* __restrict__ rp,
                              float* __restrict__ awf, int* __restrict__ idxv)
{
    __shared__ double offv[128];
    __shared__ double logit[64];
    int q = blockIdx.x, t = threadIdx.x;
    if (t < 128) {
        double s = 0.0;
        for (int k = 0; k < EE; ++k) s += (double)qe[q * EE + k] * (double)so_w[(size_t)t * EE + k];
        offv[t] = s + (double)so_b[t];
    } else if (t < 192) {
        int n = t - 128;
        double s = 0.0;
        for (int k = 0; k < EE; ++k) s += (double)qe[q * EE + k] * (double)aw_w[(size_t)n * EE + k];
        logit[n] = s + (double)aw_b[n];
    }
    __syncthreads();
    if (t < 64) {
        int hh = t >> 2, p = t & 3;
        double l0 = logit[hh * 4 + 0], l1 = logit[hh * 4 + 1];
        double l2 = logit[hh * 4 + 2], l3 = logit[hh * 4 + 3];
        double m = fmax(fmax(l0, l1), fmax(l2, l3));
        double den = exp(l0 - m) + exp(l1 - m) + exp(l2 - m) + exp(l3 - m);
        awf[(q * 16 + hh) * 4 + p] = (float)(exp(logit[hh * 4 + p] - m) / den);
        const int Wss[3] = {24, 12, 8};
        const int starts[3] = {0, 576, 720};
        double ox = offv[(hh * 4 + p) * 2 + 0], oy = offv[(hh * 4 + p) * 2 + 1];
        double rx = rp[q * 2 + 0], ry = rp[q * 2 + 1];
#pragma unroll
        for (int l = 0; l < 3; ++l) {
            int Ws = Wss[l];
            double sx = rx + ox; sx = sx < 0.0 ? 0.0 : (sx > 1.0 ? 1.0 : sx);
            double sy = ry + oy; sy = sy < 0.0 ? 0.0 : (sy > 1.0 ? 1.0 : sy);
            int x0 = (int)floor(sx * (double)(Ws - 1));
            int y0 = (int)floor(sy * (double)(Ws - 1));
            idxv[((l * 64 + q) * 16 + hh) * 4 + p] = starts[l] + y0 * Ws + x0;
        }
    }
}

// out0[b,q,h,:] = sum_{l,p} aw[q,h,p] * value[b, idx[l,q,h,p], h, :]   (bf16)
__global__ void gather_kernel(const unsigned short* __restrict__ value, const float* __restrict__ awf,
                              const int* __restrict__ idxv, unsigned short* __restrict__ out0)
{
    int unit = blockIdx.x * 4 + (threadIdx.x >> 6);
    int lane = threadIdx.x & 63;
    int b = unit >> 10;
    int rem = unit & 1023;
    int q = rem >> 4, h = rem & 15;
    float acc = 0.f;
#pragma unroll
    for (int l = 0; l < 3; ++l)
#pragma unroll
        for (int p = 0; p < 4; ++p) {
            int row = idxv[((l * 64 + q) * 16 + h) * 4 + p];
            float wgt = awf[(q * 16 + h) * 4 + p];
            acc += wgt * b2f(value[((size_t)(b * ROWS_TOT + row)) * 1024 + h * 64 + lane]);
        }
    out0[((size_t)(b * 64 + q)) * 1024 + h * 64 + lane] = f2b(acc);
}

// LN over (p0 + p1 + op_b), output bf16
__global__ void lnsum_kernel(const float* __restrict__ p0, const float* __restrict__ p1,
                             const float* __restrict__ opb, const float* __restrict__ g,
                             const float* __restrict__ bb, unsigned short* __restrict__ y)
{
    __shared__ float red[256];
    __shared__ float stats[2];
    int r = blockIdx.x, t = threadIdx.x;
    float v[4];
#pragma unroll
    for (int i = 0; i < 4; ++i) {
        int c = t + i * 256;
        size_t ix = (size_t)r * 1024 + c;
        v[i] = p0[ix] + p1[ix] + opb[c];
    }
    float s = v[0] + v[1] + v[2] + v[3];
    red[t] = s; __syncthreads();
    for (int o = 128; o; o >>= 1) { if (t < o) red[t] += red[t + o]; __syncthreads(); }
    if (t == 0) stats[0] = red[0] / 1024.f;
    __syncthreads();
    float mean = stats[0];
    float d = 0.f;
#pragma unroll
    for (int i = 0; i < 4; ++i) { float dd = v[i] - mean; d += dd * dd; }
    red[t] = d; __syncthreads();
    for (int o = 128; o; o >>= 1) { if (t < o) red[t] += red[t + o]; __syncthreads(); }
    if (t == 0) stats[1] = red[0] / 1024.f;
    __syncthreads();
    float inv = 1.f / sqrtf(stats[1] + 1e-5f);
#pragma unroll
    for (int i = 0; i < 4; ++i) {
        int c = t + i * 256;
        y[(size_t)r * 1024 + c] = f2b((v[i] - mean) * inv * g[c] + bb[c]);
    }
}

// out = p0 + p1 + fin_b (fp32)
__global__ void finred_kernel(const float* __restrict__ p0, const float* __restrict__ p1,
                              const float* __restrict__ fb, float* __restrict__ out)
{
    int idx = blockIdx.x * 256 + threadIdx.x;
    size_t e0 = (size_t)idx * 8;
    int n = (int)(e0 & 1023);
    f4 a0 = *(const f4*)(p0 + e0);
    f4 a1 = *(const f4*)(p0 + e0 + 4);
    f4 b0 = *(const f4*)(p1 + e0);
    f4 b1 = *(const f4*)(p1 + e0 + 4);
    f4 o0, o1;
#pragma unroll
    for (int i = 0; i < 4; ++i) { o0[i] = a0[i] + b0[i] + fb[n + i]; o1[i] = a1[i] + b1[i] + fb[n + 4 + i]; }
    *(f4*)(out + e0) = o0;
    *(f4*)(out + e0 + 4) = o1;
}

extern "C" void kernel_launch(void* const* d_in, const int* in_sizes, int n_in,
                              void* d_out, int out_size, void* d_ws, size_t ws_size,
                              hipStream_t stream)
{
    const float* features  = (const float*)d_in[0];
    const float* p1_w      = (const float*)d_in[1];
    const float* p1_b      = (const float*)d_in[2];
    const float* p2_w      = (const float*)d_in[3];
    const float* p2_b      = (const float*)d_in[4];
    const float* p3_w      = (const float*)d_in[5];
    const float* p3_b      = (const float*)d_in[6];
    const float* query_emb = (const float*)d_in[7];
    const float* rg_w1     = (const float*)d_in[8];
    const float* rg_b1     = (const float*)d_in[9];
    const float* rg_g      = (const float*)d_in[10];
    const float* rg_b      = (const float*)d_in[11];
    const float* rg_w2     = (const float*)d_in[12];
    const float* rg_b2     = (const float*)d_in[13];
    const float* so_w      = (const float*)d_in[14];
    const float* so_b      = (const float*)d_in[15];
    const float* aw_w      = (const float*)d_in[16];
    const float* aw_b      = (const float*)d_in[17];
    const float* vp_w      = (const float*)d_in[18];
    const float* vp_b      = (const float*)d_in[19];
    const float* op_w      = (const float*)d_in[20];
    const float* op_b      = (const float*)d_in[21];
    const float* fln_g     = (const float*)d_in[22];
    const float* fln_b     = (const float*)d_in[23];
    const float* fin_w     = (const float*)d_in[24];
    const float* fin_b     = (const float*)d_in[25];
    float* out = (float*)d_out;

    // ---- workspace layout (bytes) ----
    char* p = (char*)d_ws;
    unsigned short* FEAT = (unsigned short*)p; p += 56623104;   // bf16 [B*576,768]
    unsigned short* PT   = (unsigned short*)p; p += 22020096;   // [10752,1024] stacked p_w^T
    unsigned short* WW   = (unsigned short*)p; p += 22020096;   // [1024,10752] fused weights
    unsigned short* VPW  = (unsigned short*)p; p += 2097152;
    unsigned short* VAL  = (unsigned short*)p; p += 102760448;  // value bf16 [64*784,1024]
    float*          SCR  = (float*)p;          p += 67108864;   // PART3 (3x16.8MB) then POUT/PFIN
    unsigned short* OUT0 = (unsigned short*)p; p += 8388608;
    unsigned short* LNO  = (unsigned short*)p; p += 8388608;
    unsigned short* OPW  = (unsigned short*)p; p += 2097152;
    unsigned short* FINW = (unsigned short*)p; p += 2097152;
    float* b1p  = (float*)p; p += 4096;
    float* b2p  = (float*)p; p += 4096;
    float* b3p  = (float*)p; p += 4096;
    float* awf  = (float*)p; p += 16384;
    int*   idxv = (int*)p;   p += 49152;
    double* h0  = (double*)p; p += 524288;
    double* hb  = (double*)p; p += 524288;
    double* rp  = (double*)p; p += 1024;

    float* PART3 = SCR;                      // 3 x 4096*1024 f32
    float* POUT  = SCR;                      // 2 x 4096*1024 f32 (after reduce3 consumed)
    float* PFIN  = SCR + 2 * 4194304;

    dim3 blk(256);

    // ---- query branch (fp64, batch-independent) ----
    rg1_kernel<<<16384, blk, 0, stream>>>(query_emb, rg_w1, rg_b1, h0);
    ln_gelu_kernel<<<64, blk, 0, stream>>>(h0, rg_g, rg_b, hb);
    rp_kernel<<<32, blk, 0, stream>>>(hb, rg_w2, rg_b2, rp);
    offidx_kernel<<<64, blk, 0, stream>>>(query_emb, so_w, so_b, aw_w, aw_b, rp, awf, idxv);

    // ---- conversions ----
    f2b3_kernel<<<1536, blk, 0, stream>>>(vp_w, VPW, op_w, OPW, fin_w, FINW);
    f2b_kernel<<<13824, blk, 0, stream>>>(features, FEAT);
    fused_bias3_kernel<<<768, blk, 0, stream>>>(vp_w, vp_b, p1_b, p2_b, p3_b, b1p, b2p, b3p);
    tconv_kernel<<<dim3(24, 32),  blk, 0, stream>>>(p1_w, PT,               1024, 768);
    tconv_kernel<<<dim3(96, 32),  blk, 0, stream>>>(p2_w, PT + 768  * 1024, 1024, 3072);
    tconv_kernel<<<dim3(216, 32), blk, 0, stream>>>(p3_w, PT + 3840 * 1024, 1024, 6912);

    // ---- fused weights: WW[1024,10752] = VPW @ PT^T ----
    gemm2<true><<<dim3(84, 8), blk, 0, stream>>>(VPW, PT, nullptr, WW, 1024, WWN, 1024);

    // ---- value GEMMs, per level (balanced), level 3 split-K x3 ----
    gemm_vlv<1, false><<<dim3(8, 288),   blk, 0, stream>>>(FEAT, WW, b1p, VAL, 24);
    gemm_vlv<2, false><<<dim3(8, 72),    blk, 0, stream>>>(FEAT, WW, b2p, VAL, 96);
    gemm_vlv<3, true><<<dim3(8, 32, 3),  blk, 0, stream>>>(FEAT, WW, nullptr, PART3, 72);
    reduce3_kernel<<<2048, blk, 0, stream>>>(PART3, b3p, VAL);

    // ---- deformable gather ----
    gather_kernel<<<16384, blk, 0, stream>>>(VAL, awf, idxv, OUT0);

    // ---- output projection (split-K x2) + LN(sum) + final projection (split-K x2) ----
    gemm_pk<<<dim3(8, 32, 2), blk, 0, stream>>>(OUT0, OPW, POUT);
    lnsum_kernel<<<4096, blk, 0, stream>>>(POUT, POUT + 4194304, op_b, fln_g, fln_b, LNO);
    gemm_pk<<<dim3(8, 32, 2), blk, 0, stream>>>(LNO, FINW, PFIN);
    finred_kernel<<<2048, blk, 0, stream>>>(PFIN, PFIN + 4194304, fin_b, out);
}

// Round 5
// 581.245 us; speedup vs baseline: 1.8704x; 1.0001x over previous
//
#include <hip/hip_runtime.h>
#include <math.h>

#define EE 1024
#define ROWS_TOT 784   // 576 + 144 + 64
#define WWN 10752      // 768 + 3072 + 6912

typedef __attribute__((ext_vector_type(4))) float f4;
typedef __attribute__((ext_vector_type(4))) float f32x4;
typedef __attribute__((ext_vector_type(8))) __bf16 bf16x8;
typedef __attribute__((ext_vector_type(8))) unsigned short ushort8;

__device__ __forceinline__ unsigned short f2b(float x) {
    unsigned int u = __float_as_uint(x);
    unsigned int r = (u + 0x7fffu + ((u >> 16) & 1u)) >> 16;
    return (unsigned short)r;
}
__device__ __forceinline__ float b2f(unsigned short u) {
    unsigned int v = ((unsigned int)u) << 16;
    return __uint_as_float(v);
}

#define GLOAD16(g, l) __builtin_amdgcn_global_load_lds( \
    (const __attribute__((address_space(1))) unsigned int*)(g), \
    (__attribute__((address_space(3))) unsigned int*)(l), 16, 0, 0)

// LDS bank-conflict swizzle (both-sides involution, rule #21):
// LDS tile rows are 64B (4 x 16B segments). Stored seg s of row r holds
// global k-segment s ^ ((r>>1)&3). Staging pre-swizzles the GLOBAL source
// (linear global_load_lds dest); reads swizzle the slot index. Lanes 0-15
// of a ds_read_b128 then cover all 32 banks at 2-way (free, m136).

// ---------------------------------------------------------------------------
// 2-phase double-buffered bf16 MFMA GEMM: C[M,N] = A[M,K] @ B[N,K]^T + bias
// 128x128 tile, BK=32, 4 waves.
// ---------------------------------------------------------------------------
template<bool OB>
__global__ __launch_bounds__(256) void gemm2(
    const unsigned short* __restrict__ A, const unsigned short* __restrict__ Bw,
    const float* __restrict__ bias, void* __restrict__ Cv,
    int M, int N, int K)
{
    __shared__ unsigned short As[2][128 * 32];
    __shared__ unsigned short Bs[2][128 * 32];
    const int t = threadIdx.x;
    const int lane = t & 63;
    const int w = t >> 6;
    const int wm = w >> 1, wn = w & 1;

    int nwg = gridDim.x * gridDim.y;
    int bid = blockIdx.y * gridDim.x + blockIdx.x;
    int chunk = nwg >> 3;                    // nwg % 8 == 0 for all call sites
    int swz = (bid & 7) * chunk + (bid >> 3);
    int by = swz / gridDim.x, bx = swz % gridDim.x;
    const int m0 = by * 128, n0 = bx * 128;

    f32x4 acc[4][4] = {};

    const int sr = lane >> 2;
    const int sc = lane & 3;
    const int scx = sc ^ ((sr >> 1) & 3);            // pre-swizzled global k-segment
    const unsigned short* gA0 = A + (size_t)(m0 + w * 32 + sr) * K + scx * 8;
    const unsigned short* gA1 = gA0 + (size_t)16 * K;
    const unsigned short* gB0 = Bw + (size_t)(n0 + w * 32 + sr) * K + scx * 8;
    const unsigned short* gB1 = gB0 + (size_t)16 * K;

    const int fr = lane & 15;
    const int kg = lane >> 4;
    const int kgx = kg ^ ((fr >> 1) & 3);            // swizzled read slot

    const int nt = K >> 5;
    int cur = 0;

    auto STAGE = [&](int buf, int k0) {
        GLOAD16(gA0 + k0, &As[buf][w * 1024]);
        GLOAD16(gA1 + k0, &As[buf][w * 1024 + 512]);
        GLOAD16(gB0 + k0, &Bs[buf][w * 1024]);
        GLOAD16(gB1 + k0, &Bs[buf][w * 1024 + 512]);
    };

    STAGE(0, 0);
    __syncthreads();

    for (int tt = 0; tt < nt; ++tt) {
        if (tt + 1 < nt) STAGE(cur ^ 1, (tt + 1) * 32);
        const unsigned short* rdA = &As[cur][(wm * 64 + fr) * 32 + kgx * 8];
        const unsigned short* rdB = &Bs[cur][(wn * 64 + fr) * 32 + kgx * 8];
        bf16x8 af[4], bfr[4];
#pragma unroll
        for (int i = 0; i < 4; ++i) af[i]  = *(const bf16x8*)(rdA + i * 512);
#pragma unroll
        for (int j = 0; j < 4; ++j) bfr[j] = *(const bf16x8*)(rdB + j * 512);
#pragma unroll
        for (int i = 0; i < 4; ++i)
#pragma unroll
            for (int j = 0; j < 4; ++j)
                acc[i][j] = __builtin_amdgcn_mfma_f32_16x16x32_bf16(af[i], bfr[j], acc[i][j], 0, 0, 0);
        if (tt + 1 < nt) { __syncthreads(); cur ^= 1; }
    }

#pragma unroll
    for (int i = 0; i < 4; ++i) {
#pragma unroll
        for (int r = 0; r < 4; ++r) {
            int m = m0 + wm * 64 + i * 16 + kg * 4 + r;
#pragma unroll
            for (int j = 0; j < 4; ++j) {
                int n = n0 + wn * 64 + j * 16 + fr;
                float v = acc[i][j][r];
                if (bias) v += bias[n];
                if (OB) ((unsigned short*)Cv)[(size_t)m * N + n] = f2b(v);
                else    ((float*)Cv)[(size_t)m * N + n] = v;
            }
        }
    }
}

// ---------------------------------------------------------------------------
// Per-level value GEMM: A rows gathered from FEAT [B*576,768], B = WW slice.
// MODE 1/2/3 = level. SPLIT: write fp32 partial for K-chunk blockIdx.z.
// ---------------------------------------------------------------------------
template<int MODE, bool SPLIT>
__global__ __launch_bounds__(256) void gemm_vlv(
    const unsigned short* __restrict__ FEAT, const unsigned short* __restrict__ WW,
    const float* __restrict__ bias, void* __restrict__ outp, int ktCount)
{
    constexpr int gw = (MODE == 1) ? 24 : (MODE == 2 ? 12 : 8);
    constexpr int Rl = gw * gw;                                   // 576/144/64
    constexpr int colOff = (MODE == 1) ? 0 : (MODE == 2 ? 768 : 3840);
    constexpr int rowOff = (MODE == 1) ? 0 : (MODE == 2 ? 576 : 720);

    __shared__ unsigned short As[2][128 * 32];
    __shared__ unsigned short Bs[2][128 * 32];
    const int t = threadIdx.x;
    const int lane = t & 63;
    const int w = t >> 6;
    const int wm = w >> 1, wn = w & 1;

    int nwg = gridDim.x * gridDim.y;
    int bid = blockIdx.y * gridDim.x + blockIdx.x;
    int chunk = nwg >> 3;
    int swz = (bid & 7) * chunk + (bid >> 3);
    int by = swz / gridDim.x, bx = swz % gridDim.x;
    const int m0 = by * 128, n0 = bx * 128;
    const int ktBase = blockIdx.z * ktCount;

    f32x4 acc[4][4] = {};

    const int sr = lane >> 2;
    const int sc = lane & 3;
    const int scx = sc ^ ((sr >> 1) & 3);
    int mrow0 = m0 + w * 32 + sr;
    int mrow1 = mrow0 + 16;
    int rb0, rb1;
    if (MODE == 1) { rb0 = mrow0; rb1 = mrow1; }
    else {
        int b_ = mrow0 / Rl, rl = mrow0 - b_ * Rl;
        rb0 = b_ * 576 + (MODE * (rl / gw)) * 24 + MODE * (rl % gw);
        b_ = mrow1 / Rl; rl = mrow1 - b_ * Rl;
        rb1 = b_ * 576 + (MODE * (rl / gw)) * 24 + MODE * (rl % gw);
    }
    const unsigned short* gB0 = WW + (size_t)(n0 + w * 32 + sr) * WWN + colOff + scx * 8;
    const unsigned short* gB1 = gB0 + (size_t)16 * WWN;

    const int fr = lane & 15;
    const int kg = lane >> 4;
    const int kgx = kg ^ ((fr >> 1) & 3);
    int cur = 0;

    auto STAGE = [&](int buf, int ktl) {
        int kt = ktBase + ktl;
        int s = kt / 24;                       // which 768-chunk
        int within = (kt - s * 24) * 32;       // multiple of 32; +scx*8 stays in-row
        int add = 0;
        if (MODE == 2)      add = (s >> 1) * 24 + (s & 1);
        else if (MODE == 3) { int di = s / 3; add = di * 24 + (s - 3 * di); }
        GLOAD16(FEAT + (size_t)(rb0 + add) * 768 + within + scx * 8, &As[buf][w * 1024]);
        GLOAD16(FEAT + (size_t)(rb1 + add) * 768 + within + scx * 8, &As[buf][w * 1024 + 512]);
        GLOAD16(gB0 + (size_t)kt * 32, &Bs[buf][w * 1024]);
        GLOAD16(gB1 + (size_t)kt * 32, &Bs[buf][w * 1024 + 512]);
    };

    STAGE(0, 0);
    __syncthreads();

    for (int tt = 0; tt < ktCount; ++tt) {
        if (tt + 1 < ktCount) STAGE(cur ^ 1, tt + 1);
        const unsigned short* rdA = &As[cur][(wm * 64 + fr) * 32 + kgx * 8];
        const unsigned short* rdB = &Bs[cur][(wn * 64 + fr) * 32 + kgx * 8];
        bf16x8 af[4], bfr[4];
#pragma unroll
        for (int i = 0; i < 4; ++i) af[i]  = *(const bf16x8*)(rdA + i * 512);
#pragma unroll
        for (int j = 0; j < 4; ++j) bfr[j] = *(const bf16x8*)(rdB + j * 512);
#pragma unroll
        for (int i = 0; i < 4; ++i)
#pragma unroll
            for (int j = 0; j < 4; ++j)
                acc[i][j] = __builtin_amdgcn_mfma_f32_16x16x32_bf16(af[i], bfr[j], acc[i][j], 0, 0, 0);
        if (tt + 1 < ktCount) { __syncthreads(); cur ^= 1; }
    }

#pragma unroll
    for (int i = 0; i < 4; ++i) {
#pragma unroll
        for (int r = 0; r < 4; ++r) {
            int m = m0 + wm * 64 + i * 16 + kg * 4 + r;     // local level row
#pragma unroll
            for (int j = 0; j < 4; ++j) {
                int n = n0 + wn * 64 + j * 16 + fr;
                if (SPLIT) {
                    float* P = (float*)outp + (size_t)blockIdx.z * (4096 * 1024);
                    P[(size_t)m * EE + n] = acc[i][j][r];
                } else {
                    int b_o = m / Rl, rl_o = m - (m / Rl) * Rl;
                    int crow = b_o * ROWS_TOT + rowOff + rl_o;
                    ((unsigned short*)outp)[(size_t)crow * EE + n] = f2b(acc[i][j][r] + bias[n]);
                }
            }
        }
    }
}

// reduce level-3 split-K partials: VAL rows 720..783 per batch
__global__ void reduce3_kernel(const float* __restrict__ P, const float* __restrict__ b3,
                               unsigned short* __restrict__ VAL)
{
    int idx = blockIdx.x * 256 + threadIdx.x;   // 524288 units of 8 elems
    size_t e0 = (size_t)idx * 8;
    int m = (int)(e0 >> 10);
    int n = (int)(e0 & 1023);
    f4 a0 = *(const f4*)(P + e0);
    f4 a1 = *(const f4*)(P + e0 + 4);
    f4 c0 = *(const f4*)(P + 4194304 + e0);
    f4 c1 = *(const f4*)(P + 4194304 + e0 + 4);
    f4 d0 = *(const f4*)(P + 8388608 + e0);
    f4 d1 = *(const f4*)(P + 8388608 + e0 + 4);
    int crow = (m >> 6) * ROWS_TOT + 720 + (m & 63);
    ushort8 o;
#pragma unroll
    for (int i = 0; i < 4; ++i) o[i]     = f2b(a0[i] + c0[i] + d0[i] + b3[n + i]);
#pragma unroll
    for (int i = 0; i < 4; ++i) o[4 + i] = f2b(a1[i] + c1[i] + d1[i] + b3[n + 4 + i]);
    *(ushort8*)(VAL + (size_t)crow * EE + n) = o;
}

// split-K (z in {0,1}) partial GEMM for the two 4096x1024x1024 epilogue GEMMs
__global__ __launch_bounds__(256) void gemm_pk(
    const unsigned short* __restrict__ A, const unsigned short* __restrict__ Bw,
    float* __restrict__ P)
{
    __shared__ unsigned short As[2][128 * 32];
    __shared__ unsigned short Bs[2][128 * 32];
    const int t = threadIdx.x;
    const int lane = t & 63;
    const int w = t >> 6;
    const int wm = w >> 1, wn = w & 1;
    const int K = 1024;

    int nwg = gridDim.x * gridDim.y;
    int bid = blockIdx.y * gridDim.x + blockIdx.x;
    int chunk = nwg >> 3;
    int swz = (bid & 7) * chunk + (bid >> 3);
    int by = swz / gridDim.x, bx = swz % gridDim.x;
    const int m0 = by * 128, n0 = bx * 128;
    const int kBase = blockIdx.z * 512;

    f32x4 acc[4][4] = {};
    const int sr = lane >> 2;
    const int sc = lane & 3;
    const int scx = sc ^ ((sr >> 1) & 3);
    const unsigned short* gA0 = A + (size_t)(m0 + w * 32 + sr) * K + kBase + scx * 8;
    const unsigned short* gA1 = gA0 + (size_t)16 * K;
    const unsigned short* gB0 = Bw + (size_t)(n0 + w * 32 + sr) * K + kBase + scx * 8;
    const unsigned short* gB1 = gB0 + (size_t)16 * K;
    const int fr = lane & 15;
    const int kg = lane >> 4;
    const int kgx = kg ^ ((fr >> 1) & 3);
    int cur = 0;

    auto STAGE = [&](int buf, int k0) {
        GLOAD16(gA0 + k0, &As[buf][w * 1024]);
        GLOAD16(gA1 + k0, &As[buf][w * 1024 + 512]);
        GLOAD16(gB0 + k0, &Bs[buf][w * 1024]);
        GLOAD16(gB1 + k0, &Bs[buf][w * 1024 + 512]);
    };

    STAGE(0, 0);
    __syncthreads();
    for (int tt = 0; tt < 16; ++tt) {
        if (tt + 1 < 16) STAGE(cur ^ 1, (tt + 1) * 32);
        const unsigned short* rdA = &As[cur][(wm * 64 + fr) * 32 + kgx * 8];
        const unsigned short* rdB = &Bs[cur][(wn * 64 + fr) * 32 + kgx * 8];
        bf16x8 af[4], bfr[4];
#pragma unroll
        for (int i = 0; i < 4; ++i) af[i]  = *(const bf16x8*)(rdA + i * 512);
#pragma unroll
        for (int j = 0; j < 4; ++j) bfr[j] = *(const bf16x8*)(rdB + j * 512);
#pragma unroll
        for (int i = 0; i < 4; ++i)
#pragma unroll
            for (int j = 0; j < 4; ++j)
                acc[i][j] = __builtin_amdgcn_mfma_f32_16x16x32_bf16(af[i], bfr[j], acc[i][j], 0, 0, 0);
        if (tt + 1 < 16) { __syncthreads(); cur ^= 1; }
    }

    float* Pz = P + (size_t)blockIdx.z * (4096 * 1024);
#pragma unroll
    for (int i = 0; i < 4; ++i)
#pragma unroll
        for (int r = 0; r < 4; ++r) {
            int m = m0 + wm * 64 + i * 16 + kg * 4 + r;
#pragma unroll
            for (int j = 0; j < 4; ++j) {
                int n = n0 + wn * 64 + j * 16 + fr;
                Pz[(size_t)m * EE + n] = acc[i][j][r];
            }
        }
}

// fp32 -> bf16 straight copy (count divisible by 2048)
__global__ void f2b_kernel(const float* __restrict__ in, unsigned short* __restrict__ out) {
    size_t i = ((size_t)blockIdx.x * 256 + threadIdx.x) * 8;
    f4 a = *(const f4*)(in + i);
    f4 b = *(const f4*)(in + i + 4);
    ushort8 o;
    o[0] = f2b(a[0]); o[1] = f2b(a[1]); o[2] = f2b(a[2]); o[3] = f2b(a[3]);
    o[4] = f2b(b[0]); o[5] = f2b(b[1]); o[6] = f2b(b[2]); o[7] = f2b(b[3]);
    *(ushort8*)(out + i) = o;
}

// three 1024x1024 weight conversions in one dispatch (512 blocks each)
__global__ void f2b3_kernel(const float* __restrict__ a, unsigned short* __restrict__ oa,
                            const float* __restrict__ b, unsigned short* __restrict__ ob,
                            const float* __restrict__ c, unsigned short* __restrict__ oc) {
    int blk = blockIdx.x;
    const float* in; unsigned short* out;
    if (blk < 512)      { in = a; out = oa; }
    else if (blk < 1024){ in = b; out = ob; blk -= 512; }
    else                { in = c; out = oc; blk -= 1024; }
    size_t i = ((size_t)blk * 256 + threadIdx.x) * 8;
    f4 x = *(const f4*)(in + i);
    f4 y = *(const f4*)(in + i + 4);
    ushort8 o;
    o[0] = f2b(x[0]); o[1] = f2b(x[1]); o[2] = f2b(x[2]); o[3] = f2b(x[3]);
    o[4] = f2b(y[0]); o[5] = f2b(y[1]); o[6] = f2b(y[2]); o[7] = f2b(y[3]);
    *(ushort8*)(out + i) = o;
}

// transpose-convert: in fp32 [R,C] -> out bf16 [C,R]
__global__ void tconv_kernel(const float* __restrict__ in, unsigned short* __restrict__ out,
                             int R, int C) {
    __shared__ float tile[32][33];
    int c0 = blockIdx.x * 32, r0 = blockIdx.y * 32;
    int tx = threadIdx.x & 31, ty = threadIdx.x >> 5;
#pragma unroll
    for (int i = 0; i < 32; i += 8)
        tile[ty + i][tx] = in[(size_t)(r0 + ty + i) * C + c0 + tx];
    __syncthreads();
#pragma unroll
    for (int i = 0; i < 32; i += 8)
        out[(size_t)(c0 + ty + i) * R + r0 + tx] = f2b(tile[tx][ty + i]);
}

// three fused biases in one dispatch: b'[e] = vp_w[e,:]·pb + vp_b[e]
__global__ void fused_bias3_kernel(const float* __restrict__ vp_w, const float* __restrict__ vp_b,
                                   const float* __restrict__ pb1, const float* __restrict__ pb2,
                                   const float* __restrict__ pb3,
                                   float* __restrict__ o1, float* __restrict__ o2, float* __restrict__ o3)
{
    int blk = blockIdx.x;
    const float* pb; float* bout;
    if (blk < 256)      { pb = pb1; bout = o1; }
    else if (blk < 512) { pb = pb2; bout = o2; blk -= 256; }
    else                { pb = pb3; bout = o3; blk -= 512; }
    int e = blk * 4 + (threadIdx.x >> 6);
    int lane = threadIdx.x & 63;
    float s = 0.f;
    for (int k = lane; k < EE; k += 64) s += vp_w[(size_t)e * EE + k] * pb[k];
#pragma unroll
    for (int o = 32; o > 0; o >>= 1) s += __shfl_down(s, o, 64);
    if (lane == 0) bout[e] = s + vp_b[e];
}

// ---------------------------------------------------------------------------
// Query branch (batch-independent), fp64 — DO NOT ALTER (index-snap safety)
// ---------------------------------------------------------------------------
__global__ void rg1_kernel(const float* __restrict__ qe, const float* __restrict__ w,
                           const float* __restrict__ b, double* __restrict__ h0)
{
    int o = blockIdx.x * 4 + (threadIdx.x >> 6);
    int lane = threadIdx.x & 63;
    int q = o >> 10, n = o & 1023;
    double s = 0.0;
    for (int k = lane; k < EE; k += 64)
        s += (double)qe[q * EE + k] * (double)w[(size_t)n * EE + k];
#pragma unroll
    for (int off = 32; off > 0; off >>= 1) s += __shfl_down(s, off, 64);
    if (lane == 0) h0[o] = s + (double)b[n];
}

__global__ void ln_gelu_kernel(const double* __restrict__ h0, const float* __restrict__ g,
                               const float* __restrict__ bb, double* __restrict__ h)
{
    __shared__ double red[256];
    __shared__ double stats[2];
    int q = blockIdx.x, t = threadIdx.x;
    double x[4];
#pragma unroll
    for (int i = 0; i < 4; ++i) x[i] = h0[q * 1024 + t + i * 256];
    double s = x[0] + x[1] + x[2] + x[3];
    red[t] = s; __syncthreads();
    for (int o = 128; o; o >>= 1) { if (t < o) red[t] += red[t + o]; __syncthreads(); }
    if (t == 0) stats[0] = red[0] / 1024.0;
    __syncthreads();
    double mean = stats[0];
    double d = 0.0;
#pragma unroll
    for (int i = 0; i < 4; ++i) { double dd = x[i] - mean; d += dd * dd; }
    red[t] = d; __syncthreads();
    for (int o = 128; o; o >>= 1) { if (t < o) red[t] += red[t + o]; __syncthreads(); }
    if (t == 0) stats[1] = red[0] / 1024.0;
    __syncthreads();
    double inv = 1.0 / sqrt(stats[1] + 1e-5);
#pragma unroll
    for (int i = 0; i < 4; ++i) {
        int c = t + i * 256;
        double y = (x[i] - mean) * inv * (double)g[c] + (double)bb[c];
        h[q * 1024 + c] = y * 0.5 * (1.0 + erf(y * 0.70710678118654752440));
    }
}

__global__ void rp_kernel(const double* __restrict__ h, const float* __restrict__ w2,
                          const float* __restrict__ b2, double* __restrict__ rp)
{
    int o = blockIdx.x * 4 + (threadIdx.x >> 6);
    int lane = threadIdx.x & 63;
    int q = o >> 1, r = o & 1;
    double s = 0.0;
    for (int k = lane; k < EE; k += 64)
        s += h[q * 1024 + k] * (double)w2[r * 1024 + k];
#pragma unroll
    for (int off = 32; off > 0; off >>= 1) s += __shfl_down(s, off, 64);
    if (lane == 0) rp[o] = 1.0 / (1.0 + exp(-(s + (double)b2[r])));
}

__global__ void offidx_kernel(const float* __restrict__ qe, const float* __restrict__ so_w,
                              const float* __restrict__ so_b, const float* __restrict__ aw_w,
                              const float* __restrict__ aw_b, const double* __restrict__ rp,
                              float* __restrict__ awf, int* __restrict__ idxv)
{
    __shared__ double offv[128];
    __shared__ double logit[64];
    int q = blockIdx.x, t = threadIdx.x;
    if (t < 128) {
        double s = 0.0;
        for (int k = 0; k < EE; ++k) s += (double)qe[q * EE + k] * (double)so_w[(size_t)t * EE + k];
        offv[t] = s + (double)so_b[t];
    } else if (t < 192) {
        int n = t - 128;
        double s = 0.0;
        for (int k = 0; k < EE; ++k) s += (double)qe[q * EE + k] * (double)aw_w[(size_t)n * EE + k];
        logit[n] = s + (double)aw_b[n];
    }
    __syncthreads();
    if (t < 64) {
        int hh = t >> 2, p = t & 3;
        double l0 = logit[hh * 4 + 0], l1 = logit[hh * 4 + 1];
        double l2 = logit[hh * 4 + 2], l3 = logit[hh * 4 + 3];
        double m = fmax(fmax(l0, l1), fmax(l2, l3));
        double den = exp(l0 - m) + exp(l1 - m) + exp(l2 - m) + exp(l3 - m);
        awf[(q * 16 + hh) * 4 + p] = (float)(exp(logit[hh * 4 + p] - m) / den);
        const int Wss[3] = {24, 12, 8};
        const int starts[3] = {0, 576, 720};
        double ox = offv[(hh * 4 + p) * 2 + 0], oy = offv[(hh * 4 + p) * 2 + 1];
        double rx = rp[q * 2 + 0], ry = rp[q * 2 + 1];
#pragma unroll
        for (int l = 0; l < 3; ++l) {
            int Ws = Wss[l];
            double sx = rx + ox; sx = sx < 0.0 ? 0.0 : (sx > 1.0 ? 1.0 : sx);
            double sy = ry + oy; sy = sy < 0.0 ? 0.0 : (sy > 1.0 ? 1.0 : sy);
            int x0 = (int)floor(sx * (double)(Ws - 1));
            int y0 = (int)floor(sy * (double)(Ws - 1));
            idxv[((l * 64 + q) * 16 + hh) * 4 + p] = starts[l] + y0 * Ws + x0;
        }
    }
}

// out0[b,q,h,:] = sum_{l,p} aw[q,h,p] * value[b, idx[l,q,h,p], h, :]   (bf16)
__global__ void gather_kernel(const unsigned short* __restrict__ value, const float* __restrict__ awf,
                              const int* __restrict__ idxv, unsigned short* __restrict__ out0)
{
    int unit = blockIdx.x * 4 + (threadIdx.x >> 6);
    int lane = threadIdx.x & 63;
    int b = unit >> 10;
    int rem = unit & 1023;
    int q = rem >> 4, h = rem & 15;
    float acc = 0.f;
#pragma unroll
    for (int l = 0; l < 3; ++l)
#pragma unroll
        for (int p = 0; p < 4; ++p) {
            int row = idxv[((l * 64 + q) * 16 + h) * 4 + p];
            float wgt = awf[(q * 16 + h) * 4 + p];
            acc += wgt * b2f(value[((size_t)(b * ROWS_TOT + row)) * 1024 + h * 64 + lane]);
        }
    out0[((size_t)(b * 64 + q)) * 1024 + h * 64 + lane] = f2b(acc);
}

// LN over (p0 + p1 + op_b), output bf16
__global__ void lnsum_kernel(const float* __restrict__ p0, const float* __restrict__ p1,
                             const float* __restrict__ opb, const float* __restrict__ g,
                             const float* __restrict__ bb, unsigned short* __restrict__ y)
{
    __shared__ float red[256];
    __shared__ float stats[2];
    int r = blockIdx.x, t = threadIdx.x;
    float v[4];
#pragma unroll
    for (int i = 0; i < 4; ++i) {
        int c = t + i * 256;
        size_t ix = (size_t)r * 1024 + c;
        v[i] = p0[ix] + p1[ix] + opb[c];
    }
    float s = v[0] + v[1] + v[2] + v[3];
    red[t] = s; __syncthreads();
    for (int o = 128; o; o >>= 1) { if (t < o) red[t] += red[t + o]; __syncthreads(); }
    if (t == 0) stats[0] = red[0] / 1024.f;
    __syncthreads();
    float mean = stats[0];
    float d = 0.f;
#pragma unroll
    for (int i = 0; i < 4; ++i) { float dd = v[i] - mean; d += dd * dd; }
    red[t] = d; __syncthreads();
    for (int o = 128; o; o >>= 1) { if (t < o) red[t] += red[t + o]; __syncthreads(); }
    if (t == 0) stats[1] = red[0] / 1024.f;
    __syncthreads();
    float inv = 1.f / sqrtf(stats[1] + 1e-5f);
#pragma unroll
    for (int i = 0; i < 4; ++i) {
        int c = t + i * 256;
        y[(size_t)r * 1024 + c] = f2b((v[i] - mean) * inv * g[c] + bb[c]);
    }
}

// out = p0 + p1 + fin_b (fp32)
__global__ void finred_kernel(const float* __restrict__ p0, const float* __restrict__ p1,
                              const float* __restrict__ fb, float* __restrict__ out)
{
    int idx = blockIdx.x * 256 + threadIdx.x;
    size_t e0 = (size_t)idx * 8;
    int n = (int)(e0 & 1023);
    f4 a0 = *(const f4*)(p0 + e0);
    f4 a1 = *(const f4*)(p0 + e0 + 4);
    f4 b0 = *(const f4*)(p1 + e0);
    f4 b1 = *(const f4*)(p1 + e0 + 4);
    f4 o0, o1;
#pragma unroll
    for (int i = 0; i < 4; ++i) { o0[i] = a0[i] + b0[i] + fb[n + i]; o1[i] = a1[i] + b1[i] + fb[n + 4 + i]; }
    *(f4*)(out + e0) = o0;
    *(f4*)(out + e0 + 4) = o1;
}

extern "C" void kernel_launch(void* const* d_in, const int* in_sizes, int n_in,
                              void* d_out, int out_size, void* d_ws, size_t ws_size,
                              hipStream_t stream)
{
    const float* features  = (const float*)d_in[0];
    const float* p1_w      = (const float*)d_in[1];
    const float* p1_b      = (const float*)d_in[2];
    const float* p2_w      = (const float*)d_in[3];
    const float* p2_b      = (const float*)d_in[4];
    const float* p3_w      = (const float*)d_in[5];
    const float* p3_b      = (const float*)d_in[6];
    const float* query_emb = (const float*)d_in[7];
    const float* rg_w1     = (const float*)d_in[8];
    const float* rg_b1     = (const float*)d_in[9];
    const float* rg_g      = (const float*)d_in[10];
    const float* rg_b      = (const float*)d_in[11];
    const float* rg_w2     = (const float*)d_in[12];
    const float* rg_b2     = (const float*)d_in[13];
    const float* so_w      = (const float*)d_in[14];
    const float* so_b      = (const float*)d_in[15];
    const float* aw_w      = (const float*)d_in[16];
    const float* aw_b      = (const float*)d_in[17];
    const float* vp_w      = (const float*)d_in[18];
    const float* vp_b      = (const float*)d_in[19];
    const float* op_w      = (const float*)d_in[20];
    const float* op_b      = (const float*)d_in[21];
    const float* fln_g     = (const float*)d_in[22];
    const float* fln_b     = (const float*)d_in[23];
    const float* fin_w     = (const float*)d_in[24];
    const float* fin_b     = (const float*)d_in[25];
    float* out = (float*)d_out;

    // ---- workspace layout (bytes) ----
    char* p = (char*)d_ws;
    unsigned short* FEAT = (unsigned short*)p; p += 56623104;   // bf16 [B*576,768]
    unsigned short* PT   = (unsigned short*)p; p += 22020096;   // [10752,1024] stacked p_w^T
    unsigned short* WW   = (unsigned short*)p; p += 22020096;   // [1024,10752] fused weights
    unsigned short* VPW  = (unsigned short*)p; p += 2097152;
    unsigned short* VAL  = (unsigned short*)p; p += 102760448;  // value bf16 [64*784,1024]
    float*          SCR  = (float*)p;          p += 67108864;   // PART3 (3x16.8MB) then POUT/PFIN
    unsigned short* OUT0 = (unsigned short*)p; p += 8388608;
    unsigned short* LNO  = (unsigned short*)p; p += 8388608;
    unsigned short* OPW  = (unsigned short*)p; p += 2097152;
    unsigned short* FINW = (unsigned short*)p; p += 2097152;
    float* b1p  = (float*)p; p += 4096;
    float* b2p  = (float*)p; p += 4096;
    float* b3p  = (float*)p; p += 4096;
    float* awf  = (float*)p; p += 16384;
    int*   idxv = (int*)p;   p += 49152;
    double* h0  = (double*)p; p += 524288;
    double* hb  = (double*)p; p += 524288;
    double* rp  = (double*)p; p += 1024;

    float* PART3 = SCR;                      // 3 x 4096*1024 f32
    float* POUT  = SCR;                      // 2 x 4096*1024 f32 (after reduce3 consumed)
    float* PFIN  = SCR + 2 * 4194304;

    dim3 blk(256);

    // ---- query branch (fp64, batch-independent) ----
    rg1_kernel<<<16384, blk, 0, stream>>>(query_emb, rg_w1, rg_b1, h0);
    ln_gelu_kernel<<<64, blk, 0, stream>>>(h0, rg_g, rg_b, hb);
    rp_kernel<<<32, blk, 0, stream>>>(hb, rg_w2, rg_b2, rp);
    offidx_kernel<<<64, blk, 0, stream>>>(query_emb, so_w, so_b, aw_w, aw_b, rp, awf, idxv);

    // ---- conversions ----
    f2b3_kernel<<<1536, blk, 0, stream>>>(vp_w, VPW, op_w, OPW, fin_w, FINW);
    f2b_kernel<<<13824, blk, 0, stream>>>(features, FEAT);
    fused_bias3_kernel<<<768, blk, 0, stream>>>(vp_w, vp_b, p1_b, p2_b, p3_b, b1p, b2p, b3p);
    tconv_kernel<<<dim3(24, 32),  blk, 0, stream>>>(p1_w, PT,               1024, 768);
    tconv_kernel<<<dim3(96, 32),  blk, 0, stream>>>(p2_w, PT + 768  * 1024, 1024, 3072);
    tconv_kernel<<<dim3(216, 32), blk, 0, stream>>>(p3_w, PT + 3840 * 1024, 1024, 6912);

    // ---- fused weights: WW[1024,10752] = VPW @ PT^T ----
    gemm2<true><<<dim3(84, 8), blk, 0, stream>>>(VPW, PT, nullptr, WW, 1024, WWN, 1024);

    // ---- value GEMMs, per level (balanced), level 3 split-K x3 ----
    gemm_vlv<1, false><<<dim3(8, 288),   blk, 0, stream>>>(FEAT, WW, b1p, VAL, 24);
    gemm_vlv<2, false><<<dim3(8, 72),    blk, 0, stream>>>(FEAT, WW, b2p, VAL, 96);
    gemm_vlv<3, true><<<dim3(8, 32, 3),  blk, 0, stream>>>(FEAT, WW, nullptr, PART3, 72);
    reduce3_kernel<<<2048, blk, 0, stream>>>(PART3, b3p, VAL);

    // ---- deformable gather ----
    gather_kernel<<<16384, blk, 0, stream>>>(VAL, awf, idxv, OUT0);

    // ---- output projection (split-K x2) + LN(sum) + final projection (split-K x2) ----
    gemm_pk<<<dim3(8, 32, 2), blk, 0, stream>>>(OUT0, OPW, POUT);
    lnsum_kernel<<<4096, blk, 0, stream>>>(POUT, POUT + 4194304, op_b, fln_g, fln_b, LNO);
    gemm_pk<<<dim3(8, 32, 2), blk, 0, stream>>>(LNO, FINW, PFIN);
    finred_kernel<<<2048, blk, 0, stream>>>(PFIN, PFIN + 4194304, fin_b, out);
}